// Round 1
// baseline (797.443 us; speedup 1.0000x reference)
//
#include <hip/hip_runtime.h>

#define HIDDEN 2048
#define NB 64
#define NT 512
#define NK 49

// ---------------------------------------------------------------------------
// Kernel 1: all three skinny GEMMs in one launch.
//   C[M][49] = A[M][2048] @ W[49][2048]^T   (N padded to 64 internally)
//   blocks 0..511    : pg = h_t  @ Wg^T  (M = 32768)
//   blocks 512..1023 : ps = sent @ Ws^T  (M = 32768)
//   blocks 1024..1072: pv = V    @ Wv^T  (M = 3136)
// 64 rows per block, K-chunks of 32 staged in LDS (stride 36 = conflict-free),
// 16x16 thread grid, each thread 4 rows x 4 cols.
// ---------------------------------------------------------------------------
__global__ __launch_bounds__(256) void gemm_all(
    const float* __restrict__ h, const float* __restrict__ s,
    const float* __restrict__ V,
    const float* __restrict__ Wg, const float* __restrict__ Ws,
    const float* __restrict__ Wv,
    float* __restrict__ pg, float* __restrict__ ps, float* __restrict__ pv)
{
    int blk = blockIdx.x;
    const float* A; const float* W; float* C; int rowBase;
    if (blk < 512)       { A = h; W = Wg; C = pg; rowBase = blk * 64; }
    else if (blk < 1024) { A = s; W = Ws; C = ps; rowBase = (blk - 512) * 64; }
    else                 { A = V; W = Wv; C = pv; rowBase = (blk - 1024) * 64; }

    __shared__ float As[64][36];
    __shared__ float Bs[64][36];

    int tid = threadIdx.x;
    int rt = tid >> 4;        // 0..15  row group
    int jt = tid & 15;        // 0..15  col group
    int lr = tid >> 2;        // 0..63  staging row
    int lc = (tid & 3) * 8;   // 0,8,16,24 staging col

    const float* aPtr = A + (size_t)(rowBase + lr) * HIDDEN + lc;
    const float* wPtr = W + (size_t)lr * HIDDEN + lc;
    bool wValid = (lr < NK);

    float acc[4][4] = {};

    for (int kk = 0; kk < HIDDEN; kk += 32) {
        float4 a0 = *(const float4*)(aPtr + kk);
        float4 a1 = *(const float4*)(aPtr + kk + 4);
        float4 w0 = make_float4(0.f, 0.f, 0.f, 0.f), w1 = w0;
        if (wValid) {
            w0 = *(const float4*)(wPtr + kk);
            w1 = *(const float4*)(wPtr + kk + 4);
        }
        *(float4*)&As[lr][lc]     = a0;
        *(float4*)&As[lr][lc + 4] = a1;
        *(float4*)&Bs[lr][lc]     = w0;
        *(float4*)&Bs[lr][lc + 4] = w1;
        __syncthreads();

        #pragma unroll
        for (int u = 0; u < 32; u += 4) {
            float4 av[4], wv[4];
            #pragma unroll
            for (int i = 0; i < 4; i++) av[i] = *(const float4*)&As[rt * 4 + i][u];
            #pragma unroll
            for (int c = 0; c < 4; c++) wv[c] = *(const float4*)&Bs[jt + 16 * c][u];
            #pragma unroll
            for (int i = 0; i < 4; i++) {
                #pragma unroll
                for (int c = 0; c < 4; c++) {
                    acc[i][c] = fmaf(av[i].x, wv[c].x, acc[i][c]);
                    acc[i][c] = fmaf(av[i].y, wv[c].y, acc[i][c]);
                    acc[i][c] = fmaf(av[i].z, wv[c].z, acc[i][c]);
                    acc[i][c] = fmaf(av[i].w, wv[c].w, acc[i][c]);
                }
            }
        }
        __syncthreads();
    }

    #pragma unroll
    for (int i = 0; i < 4; i++) {
        size_t row = rowBase + rt * 4 + i;
        #pragma unroll
        for (int c = 0; c < 4; c++) {
            int j = jt + 16 * c;
            if (j < NK) C[row * NK + j] = acc[i][c];
        }
    }
}

// fast tanh: 1 - 2/(exp(2x)+1); safe at +-inf of exp
__device__ __forceinline__ float ftanh(float x) {
    float e = __expf(2.f * x);
    return 1.f - 2.f * __builtin_amdgcn_rcpf(e + 1.f);
}

// ---------------------------------------------------------------------------
// Kernel 2: per-(b,t) scores + softmaxes. One wave per row (b,t).
//   lane j (phase A): z_ext = sum_j tanh(ps+pg)*wh[j]   (wave reduce)
//   lane k (phase B): z[k]  = sum_j tanh(pv[b,k,j]+pg[j])*wh[j]
//   alpha = softmax_k(z); beta = softmax([z, z_ext])[-1]
// ---------------------------------------------------------------------------
__global__ __launch_bounds__(256) void zab_kernel(
    const float* __restrict__ pg, const float* __restrict__ ps,
    const float* __restrict__ pv, const float* __restrict__ Wh,
    float* __restrict__ alpha, float* __restrict__ beta,
    float* __restrict__ alphaT)
{
    int w = threadIdx.x >> 6, lane = threadIdx.x & 63;
    int row = blockIdx.x * 4 + w;        // 0..32767
    int b = row >> 9, t = row & 511;

    const float* pgrow = pg + (size_t)row * NK;
    const float* psrow = ps + (size_t)row * NK;

    // phase A: z_ext
    float va = 0.f;
    if (lane < NK)
        va = ftanh(psrow[lane] + pgrow[lane]) * Wh[lane];
    float z_ext = va;
    #pragma unroll
    for (int off = 32; off; off >>= 1) z_ext += __shfl_xor(z_ext, off);

    // phase B: z[k]
    float z = -1e30f;
    if (lane < NK) {
        const float* pvrow = pv + ((size_t)b * NK + lane) * NK;
        float acc = 0.f;
        for (int j = 0; j < NK; j++)
            acc = fmaf(ftanh(pvrow[j] + pgrow[j]), Wh[j], acc);
        z = acc;
    }

    // softmax over k (49)
    float m = z;
    #pragma unroll
    for (int off = 32; off; off >>= 1) m = fmaxf(m, __shfl_xor(m, off));
    float p = (lane < NK) ? __expf(z - m) : 0.f;
    float ssum = p;
    #pragma unroll
    for (int off = 32; off; off >>= 1) ssum += __shfl_xor(ssum, off);
    float a = p * __builtin_amdgcn_rcpf(ssum);

    if (lane < NK) {
        alpha[(size_t)row * NK + lane] = a;
        alphaT[((size_t)b * NK + lane) * NT + t] = a;
    }

    // extended softmax -> beta
    float me = fmaxf(m, z_ext);
    float se = ssum * __expf(m - me) + __expf(z_ext - me);
    float bet = __expf(z_ext - me) * __builtin_amdgcn_rcpf(se);
    if (lane == 0) beta[row] = bet;
}

// ---------------------------------------------------------------------------
// Kernel 3: c_hat = beta*sent + (1-beta)*(alpha @ V)
// block: (dblk 0..7, tblk 0..7, b 0..63); thread owns one d, 64 t's.
// alphaT[b][k][t] read via uniform (scalar) loads.
// ---------------------------------------------------------------------------
__global__ __launch_bounds__(256) void chat_kernel(
    const float* __restrict__ V, const float* __restrict__ sent,
    const float* __restrict__ alphaT, const float* __restrict__ beta,
    float* __restrict__ chat)
{
    int d  = blockIdx.x * 256 + threadIdx.x;
    int t0 = blockIdx.y * 64;
    int b  = blockIdx.z;

    __shared__ float beta_s[64];
    if (threadIdx.x < 64) beta_s[threadIdx.x] = beta[(size_t)b * NT + t0 + threadIdx.x];
    __syncthreads();

    float acc[64];
    #pragma unroll
    for (int t = 0; t < 64; t++) acc[t] = 0.f;

    const float* vp = V + (size_t)b * NK * HIDDEN + d;
    const float* ap = alphaT + (size_t)b * NK * NT + t0;
    for (int k = 0; k < NK; k++) {
        float v = vp[(size_t)k * HIDDEN];
        const float* a = ap + (size_t)k * NT;
        #pragma unroll
        for (int t = 0; t < 64; t++) acc[t] = fmaf(a[t], v, acc[t]);
    }

    const float* sp = sent + ((size_t)b * NT + t0) * HIDDEN + d;
    float* op = chat + ((size_t)b * NT + t0) * HIDDEN + d;
    #pragma unroll
    for (int t = 0; t < 64; t++) {
        float bt = beta_s[t];
        float sv = sp[(size_t)t * HIDDEN];
        op[(size_t)t * HIDDEN] = fmaf(bt, sv, (1.f - bt) * acc[t]);
    }
}

extern "C" void kernel_launch(void* const* d_in, const int* in_sizes, int n_in,
                              void* d_out, int out_size, void* d_ws, size_t ws_size,
                              hipStream_t stream)
{
    const float* V    = (const float*)d_in[0];
    const float* h_t  = (const float*)d_in[1];
    const float* sent = (const float*)d_in[2];
    const float* Wv   = (const float*)d_in[3];
    const float* Wg   = (const float*)d_in[4];
    const float* Ws   = (const float*)d_in[5];
    const float* Wh   = (const float*)d_in[6];

    float* out   = (float*)d_out;
    float* chat  = out;                                   // B*T*HIDDEN
    float* alpha = out + (size_t)NB * NT * HIDDEN;        // B*T*K
    float* beta  = alpha + (size_t)NB * NT * NK;          // B*T

    float* ws     = (float*)d_ws;
    float* pg     = ws;                                   // B*T*K
    float* ps     = pg + (size_t)NB * NT * NK;            // B*T*K
    float* pv     = ps + (size_t)NB * NT * NK;            // B*K*K
    float* alphaT = pv + (size_t)NB * NK * NK;            // B*K*T

    // 512 (pg) + 512 (ps) + 49 (pv) blocks
    gemm_all<<<1073, 256, 0, stream>>>(h_t, sent, V, Wg, Ws, Wv, pg, ps, pv);
    zab_kernel<<<(NB * NT) / 4, 256, 0, stream>>>(pg, ps, pv, Wh, alpha, beta, alphaT);
    chat_kernel<<<dim3(HIDDEN / 256, NT / 64, NB), 256, 0, stream>>>(V, sent, alphaT, beta, chat);
}

// Round 2
// 531.943 us; speedup vs baseline: 1.4991x; 1.4991x over previous
//
#include <hip/hip_runtime.h>

#define HIDDEN 2048
#define NB 64
#define NT 512
#define NK 49

// ---------------------------------------------------------------------------
// Kernel 1: all three skinny GEMMs in one launch.
//   C[M][49] = A[M][2048] @ W[49][2048]^T   (N padded to 64 internally)
//   blocks 0..511    : pg = h_t  @ Wg^T  (M = 32768)
//   blocks 512..1023 : ps = sent @ Ws^T  (M = 32768)
//   blocks 1024..1072: pv = V    @ Wv^T  (M = 3136)
// ---------------------------------------------------------------------------
__global__ __launch_bounds__(256) void gemm_all(
    const float* __restrict__ h, const float* __restrict__ s,
    const float* __restrict__ V,
    const float* __restrict__ Wg, const float* __restrict__ Ws,
    const float* __restrict__ Wv,
    float* __restrict__ pg, float* __restrict__ ps, float* __restrict__ pv)
{
    int blk = blockIdx.x;
    const float* A; const float* W; float* C; int rowBase;
    if (blk < 512)       { A = h; W = Wg; C = pg; rowBase = blk * 64; }
    else if (blk < 1024) { A = s; W = Ws; C = ps; rowBase = (blk - 512) * 64; }
    else                 { A = V; W = Wv; C = pv; rowBase = (blk - 1024) * 64; }

    __shared__ float As[64][36];
    __shared__ float Bs[64][36];

    int tid = threadIdx.x;
    int rt = tid >> 4;        // 0..15  row group
    int jt = tid & 15;        // 0..15  col group
    int lr = tid >> 2;        // 0..63  staging row
    int lc = (tid & 3) * 8;   // 0,8,16,24 staging col

    const float* aPtr = A + (size_t)(rowBase + lr) * HIDDEN + lc;
    const float* wPtr = W + (size_t)lr * HIDDEN + lc;
    bool wValid = (lr < NK);

    float acc[4][4] = {};

    for (int kk = 0; kk < HIDDEN; kk += 32) {
        float4 a0 = *(const float4*)(aPtr + kk);
        float4 a1 = *(const float4*)(aPtr + kk + 4);
        float4 w0 = make_float4(0.f, 0.f, 0.f, 0.f), w1 = w0;
        if (wValid) {
            w0 = *(const float4*)(wPtr + kk);
            w1 = *(const float4*)(wPtr + kk + 4);
        }
        *(float4*)&As[lr][lc]     = a0;
        *(float4*)&As[lr][lc + 4] = a1;
        *(float4*)&Bs[lr][lc]     = w0;
        *(float4*)&Bs[lr][lc + 4] = w1;
        __syncthreads();

        #pragma unroll
        for (int u = 0; u < 32; u += 4) {
            float4 av[4], wv[4];
            #pragma unroll
            for (int i = 0; i < 4; i++) av[i] = *(const float4*)&As[rt * 4 + i][u];
            #pragma unroll
            for (int c = 0; c < 4; c++) wv[c] = *(const float4*)&Bs[jt + 16 * c][u];
            #pragma unroll
            for (int i = 0; i < 4; i++) {
                #pragma unroll
                for (int c = 0; c < 4; c++) {
                    acc[i][c] = fmaf(av[i].x, wv[c].x, acc[i][c]);
                    acc[i][c] = fmaf(av[i].y, wv[c].y, acc[i][c]);
                    acc[i][c] = fmaf(av[i].z, wv[c].z, acc[i][c]);
                    acc[i][c] = fmaf(av[i].w, wv[c].w, acc[i][c]);
                }
            }
        }
        __syncthreads();
    }

    #pragma unroll
    for (int i = 0; i < 4; i++) {
        size_t row = rowBase + rt * 4 + i;
        #pragma unroll
        for (int c = 0; c < 4; c++) {
            int j = jt + 16 * c;
            if (j < NK) C[row * NK + j] = acc[i][c];
        }
    }
}

// fast tanh: 1 - 2/(exp(2x)+1); safe at +-inf of exp
__device__ __forceinline__ float ftanh(float x) {
    float e = __expf(2.f * x);
    return 1.f - 2.f * __builtin_amdgcn_rcpf(e + 1.f);
}

// ---------------------------------------------------------------------------
// Kernel 2: per-(b,t) scores + softmaxes. One wave per row (b,t).
// ---------------------------------------------------------------------------
__global__ __launch_bounds__(256) void zab_kernel(
    const float* __restrict__ pg, const float* __restrict__ ps,
    const float* __restrict__ pv, const float* __restrict__ Wh,
    float* __restrict__ alpha, float* __restrict__ beta)
{
    int w = threadIdx.x >> 6, lane = threadIdx.x & 63;
    int row = blockIdx.x * 4 + w;        // 0..32767
    int b = row >> 9;

    const float* pgrow = pg + (size_t)row * NK;
    const float* psrow = ps + (size_t)row * NK;

    // phase A: z_ext
    float va = 0.f;
    if (lane < NK)
        va = ftanh(psrow[lane] + pgrow[lane]) * Wh[lane];
    float z_ext = va;
    #pragma unroll
    for (int off = 32; off; off >>= 1) z_ext += __shfl_xor(z_ext, off);

    // phase B: z[k]
    float z = -1e30f;
    if (lane < NK) {
        const float* pvrow = pv + ((size_t)b * NK + lane) * NK;
        float acc = 0.f;
        for (int j = 0; j < NK; j++)
            acc = fmaf(ftanh(pvrow[j] + pgrow[j]), Wh[j], acc);
        z = acc;
    }

    // softmax over k (49)
    float m = z;
    #pragma unroll
    for (int off = 32; off; off >>= 1) m = fmaxf(m, __shfl_xor(m, off));
    float p = (lane < NK) ? __expf(z - m) : 0.f;
    float ssum = p;
    #pragma unroll
    for (int off = 32; off; off >>= 1) ssum += __shfl_xor(ssum, off);
    float a = p * __builtin_amdgcn_rcpf(ssum);

    if (lane < NK)
        alpha[(size_t)row * NK + lane] = a;

    // extended softmax -> beta
    float me = fmaxf(m, z_ext);
    float se = ssum * __expf(m - me) + __expf(z_ext - me);
    float bet = __expf(z_ext - me) * __builtin_amdgcn_rcpf(se);
    if (lane == 0) beta[row] = bet;
}

// ---------------------------------------------------------------------------
// Kernel 3 v2: c_hat = beta*sent + (1-beta)*(alpha @ V)
// Block tile 32t x 128d; thread owns 4t x 4d (tx=d-group 0..31, ty=t-group 0..7).
// alpha staged TRANSPOSED in LDS [49][36] -> float4 read [k][ty*4] is
// 16B-aligned, banks 4*ty mod 32 distinct (conflict-free).
// V read as float4 from global (per-b V = 400KB, L2/L3-hot).
// ---------------------------------------------------------------------------
__global__ __launch_bounds__(256) void chat_kernel(
    const float* __restrict__ V, const float* __restrict__ sent,
    const float* __restrict__ alpha, const float* __restrict__ beta,
    float* __restrict__ chat)
{
    int d0 = blockIdx.x * 128;
    int t0 = blockIdx.y * 32;
    int b  = blockIdx.z;

    __shared__ float alpha_s[NK][36];   // transposed: [k][t], stride 36
    __shared__ float beta_s[32];

    int tid = threadIdx.x;

    const float* arow = alpha + ((size_t)b * NT + t0) * NK;  // 1568 contiguous
    for (int i = tid; i < 32 * NK; i += 256) {
        int t = i / NK, k = i - t * NK;
        alpha_s[k][t] = arow[i];
    }
    if (tid < 32) beta_s[tid] = beta[(size_t)b * NT + t0 + tid];
    __syncthreads();

    int tx = tid & 31;          // d-group: d = d0 + tx*4
    int ty = tid >> 5;          // t-group: t = t0 + ty*4 + i

    const float* vp = V + (size_t)b * NK * HIDDEN + d0 + tx * 4;

    float4 acc[4];
    #pragma unroll
    for (int i = 0; i < 4; i++) acc[i] = make_float4(0.f, 0.f, 0.f, 0.f);

    #pragma unroll 7
    for (int k = 0; k < NK; k++) {
        float4 vv = *(const float4*)(vp + (size_t)k * HIDDEN);
        float4 a4 = *(const float4*)&alpha_s[k][ty * 4];
        acc[0].x = fmaf(a4.x, vv.x, acc[0].x);
        acc[0].y = fmaf(a4.x, vv.y, acc[0].y);
        acc[0].z = fmaf(a4.x, vv.z, acc[0].z);
        acc[0].w = fmaf(a4.x, vv.w, acc[0].w);
        acc[1].x = fmaf(a4.y, vv.x, acc[1].x);
        acc[1].y = fmaf(a4.y, vv.y, acc[1].y);
        acc[1].z = fmaf(a4.y, vv.z, acc[1].z);
        acc[1].w = fmaf(a4.y, vv.w, acc[1].w);
        acc[2].x = fmaf(a4.z, vv.x, acc[2].x);
        acc[2].y = fmaf(a4.z, vv.y, acc[2].y);
        acc[2].z = fmaf(a4.z, vv.z, acc[2].z);
        acc[2].w = fmaf(a4.z, vv.w, acc[2].w);
        acc[3].x = fmaf(a4.w, vv.x, acc[3].x);
        acc[3].y = fmaf(a4.w, vv.y, acc[3].y);
        acc[3].z = fmaf(a4.w, vv.z, acc[3].z);
        acc[3].w = fmaf(a4.w, vv.w, acc[3].w);
    }

    #pragma unroll
    for (int i = 0; i < 4; i++) {
        int t = ty * 4 + i;
        float bt = beta_s[t];
        const float* sp = sent + ((size_t)b * NT + t0 + t) * HIDDEN + d0 + tx * 4;
        float*       op = chat + ((size_t)b * NT + t0 + t) * HIDDEN + d0 + tx * 4;
        float4 sv = *(const float4*)sp;
        float4 o;
        o.x = fmaf(bt, sv.x, (1.f - bt) * acc[i].x);
        o.y = fmaf(bt, sv.y, (1.f - bt) * acc[i].y);
        o.z = fmaf(bt, sv.z, (1.f - bt) * acc[i].z);
        o.w = fmaf(bt, sv.w, (1.f - bt) * acc[i].w);
        *(float4*)op = o;
    }
}

extern "C" void kernel_launch(void* const* d_in, const int* in_sizes, int n_in,
                              void* d_out, int out_size, void* d_ws, size_t ws_size,
                              hipStream_t stream)
{
    const float* V    = (const float*)d_in[0];
    const float* h_t  = (const float*)d_in[1];
    const float* sent = (const float*)d_in[2];
    const float* Wv   = (const float*)d_in[3];
    const float* Wg   = (const float*)d_in[4];
    const float* Ws   = (const float*)d_in[5];
    const float* Wh   = (const float*)d_in[6];

    float* out   = (float*)d_out;
    float* chat  = out;                                   // B*T*HIDDEN
    float* alpha = out + (size_t)NB * NT * HIDDEN;        // B*T*K
    float* beta  = alpha + (size_t)NB * NT * NK;          // B*T

    float* ws     = (float*)d_ws;
    float* pg     = ws;                                   // B*T*K
    float* ps     = pg + (size_t)NB * NT * NK;            // B*T*K
    float* pv     = ps + (size_t)NB * NT * NK;            // B*K*K

    gemm_all<<<1073, 256, 0, stream>>>(h_t, sent, V, Wg, Ws, Wv, pg, ps, pv);
    zab_kernel<<<(NB * NT) / 4, 256, 0, stream>>>(pg, ps, pv, Wh, alpha, beta);
    chat_kernel<<<dim3(HIDDEN / 128, NT / 32, NB), 256, 0, stream>>>(V, sent, alpha, beta, chat);
}

// Round 3
// 387.034 us; speedup vs baseline: 2.0604x; 1.3744x over previous
//
#include <hip/hip_runtime.h>

#define HIDDEN 2048
#define NB 64
#define NT 512
#define NK 49

typedef __attribute__((ext_vector_type(4))) float f32x4;
typedef __attribute__((ext_vector_type(8))) short short8;

__device__ __forceinline__ unsigned cvtpk_bf16(float a, float b) {
    unsigned r;
    asm("v_cvt_pk_bf16_f32 %0, %1, %2" : "=v"(r) : "v"(a), "v"(b));
    return r;
}

// scalar RNE f32->bf16 (convert kernel only; not perf-critical)
__device__ __forceinline__ unsigned short f2bf(float x) {
    union { float f; unsigned u; } v; v.f = x;
    unsigned r = v.u + 0x7FFF + ((v.u >> 16) & 1);
    return (unsigned short)(r >> 16);
}

// ---------------------------------------------------------------------------
// Kernel 0: convert + swizzle W{g,s,v} (fp32 [49][2048]) into MFMA B-fragment
// order, padded to 64 cols with zeros:
//   Wf[m][ (c*64 + s)*64 + lane ][j]  (8 bf16 = 16B per entry)
//     = W_m[c*16 + (lane&15)][ s*32 + (lane>>4)*8 + j ]
// One thread per fragment entry: 3*4*64*64 = 49152 threads.
// ---------------------------------------------------------------------------
__global__ __launch_bounds__(256) void convert_w(
    const float* __restrict__ Wg, const float* __restrict__ Ws,
    const float* __restrict__ Wv, unsigned short* __restrict__ Wf)
{
    int tau = blockIdx.x * 256 + threadIdx.x;      // 0..49151
    int m   = tau >> 14;
    int rem = tau & 16383;
    int c   = rem >> 12;
    int s   = (rem >> 6) & 63;
    int l   = rem & 63;
    int col = c * 16 + (l & 15);
    int k0  = s * 32 + ((l >> 4) << 3);

    const float* W = (m == 0) ? Wg : (m == 1) ? Ws : Wv;
    unsigned short out[8];
    if (col < NK) {
        const float* p = W + (size_t)col * HIDDEN + k0;
        #pragma unroll
        for (int j = 0; j < 8; j++) out[j] = f2bf(p[j]);
    } else {
        #pragma unroll
        for (int j = 0; j < 8; j++) out[j] = 0;
    }
    unsigned short* dst = Wf + (size_t)tau * 8;
    #pragma unroll
    for (int j = 0; j < 8; j++) dst[j] = out[j];
}

// ---------------------------------------------------------------------------
// Kernel 1: MFMA GEMM, no LDS. One wave = 16 output rows x 64 cols (49 kept).
//   waves 0..2047   : pg = h    @ Wg^T
//   waves 2048..4095: ps = sent @ Ws^T
//   waves 4096..4291: pv = V    @ Wv^T
// Per k-step (32): 2x float4 A loads (full-line coalesced across the wave),
// 4x cvt_pk f32->bf16, 4 coalesced 16B B-frag loads (L2-hot), 4 MFMAs.
// ---------------------------------------------------------------------------
__global__ __launch_bounds__(256) void gemm_mfma(
    const float* __restrict__ h, const float* __restrict__ s,
    const float* __restrict__ V, const unsigned short* __restrict__ Wf,
    float* __restrict__ pg, float* __restrict__ ps, float* __restrict__ pv)
{
    int w = threadIdx.x >> 6, lane = threadIdx.x & 63;
    int gw = blockIdx.x * 4 + w;

    const float* A; float* C; int rowBase; const unsigned short* wf;
    if (gw < 2048)      { A = h; C = pg; rowBase = gw * 16;          wf = Wf; }
    else if (gw < 4096) { A = s; C = ps; rowBase = (gw - 2048) * 16; wf = Wf + (size_t)16384 * 8; }
    else                { A = V; C = pv; rowBase = (gw - 4096) * 16; wf = Wf + (size_t)32768 * 8; }

    const float* ap = A + (size_t)(rowBase + (lane & 15)) * HIDDEN + ((lane >> 4) << 3);
    const short8* bp = (const short8*)(wf + (size_t)lane * 8);
    // b-frag for (c, st): bp + (c*64 + st)*64    (in short8 units)

    f32x4 acc0 = {0.f, 0.f, 0.f, 0.f};
    f32x4 acc1 = acc0, acc2 = acc0, acc3 = acc0;

    #pragma unroll 2
    for (int st = 0; st < 64; st++) {
        float4 f0 = *(const float4*)(ap + st * 32);
        float4 f1 = *(const float4*)(ap + st * 32 + 4);

        union { short8 v; unsigned u[4]; } a;
        a.u[0] = cvtpk_bf16(f0.x, f0.y);
        a.u[1] = cvtpk_bf16(f0.z, f0.w);
        a.u[2] = cvtpk_bf16(f1.x, f1.y);
        a.u[3] = cvtpk_bf16(f1.z, f1.w);

        short8 b0 = bp[(0 * 64 + st) * 64];
        short8 b1 = bp[(1 * 64 + st) * 64];
        short8 b2 = bp[(2 * 64 + st) * 64];
        short8 b3 = bp[(3 * 64 + st) * 64];

        acc0 = __builtin_amdgcn_mfma_f32_16x16x32_bf16(a.v, b0, acc0, 0, 0, 0);
        acc1 = __builtin_amdgcn_mfma_f32_16x16x32_bf16(a.v, b1, acc1, 0, 0, 0);
        acc2 = __builtin_amdgcn_mfma_f32_16x16x32_bf16(a.v, b2, acc2, 0, 0, 0);
        acc3 = __builtin_amdgcn_mfma_f32_16x16x32_bf16(a.v, b3, acc3, 0, 0, 0);
    }

    // C/D layout (verified m89): col = lane&15, row = (lane>>4)*4 + reg
    int colb  = lane & 15;
    int rquad = (lane >> 4) << 2;
    float* crow = C + (size_t)(rowBase + rquad) * NK + colb;
    #pragma unroll
    for (int r = 0; r < 4; r++) {
        crow[(size_t)r * NK + 0]  = acc0[r];
        crow[(size_t)r * NK + 16] = acc1[r];
        crow[(size_t)r * NK + 32] = acc2[r];
    }
    if (colb == 0) {
        #pragma unroll
        for (int r = 0; r < 4; r++) crow[(size_t)r * NK + 48] = acc3[r];
    }
}

// fast tanh: 1 - 2/(exp(2x)+1); safe at +-inf of exp
__device__ __forceinline__ float ftanh(float x) {
    float e = __expf(2.f * x);
    return 1.f - 2.f * __builtin_amdgcn_rcpf(e + 1.f);
}

// ---------------------------------------------------------------------------
// Kernel 2: per-(b,t) scores + softmaxes. One wave per row (b,t).
// ---------------------------------------------------------------------------
__global__ __launch_bounds__(256) void zab_kernel(
    const float* __restrict__ pg, const float* __restrict__ ps,
    const float* __restrict__ pv, const float* __restrict__ Wh,
    float* __restrict__ alpha, float* __restrict__ beta)
{
    int w = threadIdx.x >> 6, lane = threadIdx.x & 63;
    int row = blockIdx.x * 4 + w;        // 0..32767
    int b = row >> 9;

    const float* pgrow = pg + (size_t)row * NK;
    const float* psrow = ps + (size_t)row * NK;

    // phase A: z_ext
    float va = 0.f;
    if (lane < NK)
        va = ftanh(psrow[lane] + pgrow[lane]) * Wh[lane];
    float z_ext = va;
    #pragma unroll
    for (int off = 32; off; off >>= 1) z_ext += __shfl_xor(z_ext, off);

    // phase B: z[k]
    float z = -1e30f;
    if (lane < NK) {
        const float* pvrow = pv + ((size_t)b * NK + lane) * NK;
        float acc = 0.f;
        for (int j = 0; j < NK; j++)
            acc = fmaf(ftanh(pvrow[j] + pgrow[j]), Wh[j], acc);
        z = acc;
    }

    // softmax over k (49)
    float m = z;
    #pragma unroll
    for (int off = 32; off; off >>= 1) m = fmaxf(m, __shfl_xor(m, off));
    float p = (lane < NK) ? __expf(z - m) : 0.f;
    float ssum = p;
    #pragma unroll
    for (int off = 32; off; off >>= 1) ssum += __shfl_xor(ssum, off);
    float a = p * __builtin_amdgcn_rcpf(ssum);

    if (lane < NK)
        alpha[(size_t)row * NK + lane] = a;

    // extended softmax -> beta
    float me = fmaxf(m, z_ext);
    float se = ssum * __expf(m - me) + __expf(z_ext - me);
    float bet = __expf(z_ext - me) * __builtin_amdgcn_rcpf(se);
    if (lane == 0) beta[row] = bet;
}

// ---------------------------------------------------------------------------
// Kernel 3: c_hat = beta*sent + (1-beta)*(alpha @ V)
// Block tile 32t x 128d; thread owns 4t x 4d.
// ---------------------------------------------------------------------------
__global__ __launch_bounds__(256) void chat_kernel(
    const float* __restrict__ V, const float* __restrict__ sent,
    const float* __restrict__ alpha, const float* __restrict__ beta,
    float* __restrict__ chat)
{
    int d0 = blockIdx.x * 128;
    int t0 = blockIdx.y * 32;
    int b  = blockIdx.z;

    __shared__ float alpha_s[NK][36];   // transposed: [k][t], stride 36
    __shared__ float beta_s[32];

    int tid = threadIdx.x;

    const float* arow = alpha + ((size_t)b * NT + t0) * NK;  // 1568 contiguous
    for (int i = tid; i < 32 * NK; i += 256) {
        int t = i / NK, k = i - t * NK;
        alpha_s[k][t] = arow[i];
    }
    if (tid < 32) beta_s[tid] = beta[(size_t)b * NT + t0 + tid];
    __syncthreads();

    int tx = tid & 31;          // d-group: d = d0 + tx*4
    int ty = tid >> 5;          // t-group: t = t0 + ty*4 + i

    const float* vp = V + (size_t)b * NK * HIDDEN + d0 + tx * 4;

    float4 acc[4];
    #pragma unroll
    for (int i = 0; i < 4; i++) acc[i] = make_float4(0.f, 0.f, 0.f, 0.f);

    #pragma unroll 7
    for (int k = 0; k < NK; k++) {
        float4 vv = *(const float4*)(vp + (size_t)k * HIDDEN);
        float4 a4 = *(const float4*)&alpha_s[k][ty * 4];
        acc[0].x = fmaf(a4.x, vv.x, acc[0].x);
        acc[0].y = fmaf(a4.x, vv.y, acc[0].y);
        acc[0].z = fmaf(a4.x, vv.z, acc[0].z);
        acc[0].w = fmaf(a4.x, vv.w, acc[0].w);
        acc[1].x = fmaf(a4.y, vv.x, acc[1].x);
        acc[1].y = fmaf(a4.y, vv.y, acc[1].y);
        acc[1].z = fmaf(a4.y, vv.z, acc[1].z);
        acc[1].w = fmaf(a4.y, vv.w, acc[1].w);
        acc[2].x = fmaf(a4.z, vv.x, acc[2].x);
        acc[2].y = fmaf(a4.z, vv.y, acc[2].y);
        acc[2].z = fmaf(a4.z, vv.z, acc[2].z);
        acc[2].w = fmaf(a4.z, vv.w, acc[2].w);
        acc[3].x = fmaf(a4.w, vv.x, acc[3].x);
        acc[3].y = fmaf(a4.w, vv.y, acc[3].y);
        acc[3].z = fmaf(a4.w, vv.z, acc[3].z);
        acc[3].w = fmaf(a4.w, vv.w, acc[3].w);
    }

    #pragma unroll
    for (int i = 0; i < 4; i++) {
        int t = ty * 4 + i;
        float bt = beta_s[t];
        const float* sp = sent + ((size_t)b * NT + t0 + t) * HIDDEN + d0 + tx * 4;
        float*       op = chat + ((size_t)b * NT + t0 + t) * HIDDEN + d0 + tx * 4;
        float4 sv = *(const float4*)sp;
        float4 o;
        o.x = fmaf(bt, sv.x, (1.f - bt) * acc[i].x);
        o.y = fmaf(bt, sv.y, (1.f - bt) * acc[i].y);
        o.z = fmaf(bt, sv.z, (1.f - bt) * acc[i].z);
        o.w = fmaf(bt, sv.w, (1.f - bt) * acc[i].w);
        *(float4*)op = o;
    }
}

extern "C" void kernel_launch(void* const* d_in, const int* in_sizes, int n_in,
                              void* d_out, int out_size, void* d_ws, size_t ws_size,
                              hipStream_t stream)
{
    const float* V    = (const float*)d_in[0];
    const float* h_t  = (const float*)d_in[1];
    const float* sent = (const float*)d_in[2];
    const float* Wv   = (const float*)d_in[3];
    const float* Wg   = (const float*)d_in[4];
    const float* Ws   = (const float*)d_in[5];
    const float* Wh   = (const float*)d_in[6];

    float* out   = (float*)d_out;
    float* chat  = out;                                   // B*T*HIDDEN
    float* alpha = out + (size_t)NB * NT * HIDDEN;        // B*T*K
    float* beta  = alpha + (size_t)NB * NT * NK;          // B*T

    float* ws = (float*)d_ws;
    float* pg = ws;                                       // 32768*49
    float* ps = pg + (size_t)NB * NT * NK;                // 32768*49
    float* pv = ps + (size_t)NB * NT * NK;                // 3136*49
    unsigned short* Wf = (unsigned short*)(pv + (size_t)NB * NK * NK); // 3*16384*8 bf16

    convert_w<<<192, 256, 0, stream>>>(Wg, Ws, Wv, Wf);
    gemm_mfma<<<1073, 256, 0, stream>>>(h_t, sent, V, Wf, pg, ps, pv);
    zab_kernel<<<(NB * NT) / 4, 256, 0, stream>>>(pg, ps, pv, Wh, alpha, beta);
    chat_kernel<<<dim3(HIDDEN / 128, NT / 32, NB), 256, 0, stream>>>(V, sent, alpha, beta, chat);
}